// Round 7
// baseline (88.317 us; speedup 1.0000x reference)
//
#include <hip/hip_runtime.h>
#include <hip/hip_bf16.h>

typedef __attribute__((ext_vector_type(8))) short short8;
typedef __attribute__((ext_vector_type(4))) float f32x4;

#define B_SZ 64
#define T_SZ 8192
#define D_SZ 128
#define U_SZ 128
#define T_TILE 64
#define GRID_P 1024
#define TILES_PER_BLK 8           /* 1024 blocks x 8 tiles x 64 rows = 64*8192 */
#define P_STRIDE 132              /* c[128] + m + s, padded */
#define WT_LD 136                 /* bf16 row stride: 272B */

__device__ __forceinline__ unsigned short f2bf(float f) {
  unsigned int u = __builtin_bit_cast(unsigned int, f);
  u += 0x7fffu + ((u >> 16) & 1u);
  return (unsigned short)(u >> 16);
}

__device__ __forceinline__ float bf2f(unsigned short s) {
  return __builtin_bit_cast(float, (unsigned int)s << 16);
}

__device__ __forceinline__ float fast_tanh(float x) {
  float e = __expf(2.0f * x);
  return 1.0f - 2.0f * __builtin_amdgcn_rcpf(e + 1.0f);
}

// DPP row-reduce within each 16-lane row (VALU pipe only).
template<int CTRL>
__device__ __forceinline__ float dpp_add(float v) {
  int t = __builtin_amdgcn_update_dpp(0, __builtin_bit_cast(int, v),
                                      CTRL, 0xf, 0xf, true);
  return v + __builtin_bit_cast(float, t);
}
__device__ __forceinline__ float row_reduce16(float v) {
  v = dpp_add<0x118>(v);  // row_shr:8
  v = dpp_add<0x114>(v);  // row_shr:4
  v = dpp_add<0x112>(v);  // row_shr:2
  v = dpp_add<0x111>(v);  // row_shr:1
  return v;               // lane lr==15 of each 16-lane row holds the sum
}

__device__ __forceinline__ void cvt_tile(const float4 pf[8], short8 afrag[4]) {
#pragma unroll
  for (int kt = 0; kt < 4; ++kt) {
    short8 a;
#pragma unroll
    for (int j = 0; j < 4; ++j) {
      float4 f = pf[kt * 2 + (j >> 1)];
      a[j * 2]     = (short)f2bf(j & 1 ? f.z : f.x);
      a[j * 2 + 1] = (short)f2bf(j & 1 ? f.w : f.y);
    }
    afrag[kt] = a;
  }
}

// ---------------------------------------------------------------------------
// Kernel 0: W [d][u] fp32 -> Wt [u][d] bf16 in workspace (once, tiny)
// ---------------------------------------------------------------------------
__global__ void k_prep(const float* __restrict__ wk, unsigned short* __restrict__ wt) {
  int i = blockIdx.x * 256 + threadIdx.x;
  if (i < D_SZ * U_SZ) {
    int d = i >> 7, u = i & 127;
    wt[u * D_SZ + d] = f2bf(wk[i]);
  }
}

// ---------------------------------------------------------------------------
// Kernel 1: 1024 blocks x 8 contiguous 64-row tiles. ZERO barriers in the
// tile loop: each wave runs a private online softmax over its own 16 rows
// per tile (wave-private LDS logits slice needs only lgkmcnt, which does NOT
// drain vmcnt), and accumulates its running context in registers (rc, valid
// at lr==15 lanes). The next tile's fp32 loads therefore stay in flight
// across the entire loop body -> HBM streams continuously (R5 stalled on
// the s_waitcnt vmcnt(0) the compiler emits before every s_barrier).
// Cross-wave merge happens once, after the loop.
// ---------------------------------------------------------------------------
__global__ __launch_bounds__(256) void k_partial(
    const float* __restrict__ x, const unsigned short* __restrict__ wt_g,
    const float* __restrict__ wb, const float* __restrict__ v,
    const float* __restrict__ vb, float* __restrict__ pbuf)
{
  __shared__ unsigned short wt[U_SZ][WT_LD];  // 34816 B
  __shared__ float wb_s[U_SZ], v_s[U_SZ];     // 1 KB
  __shared__ float logits[4][16];             // wave-private slices
  __shared__ float fin[4][D_SZ];              // final merge buffers
  __shared__ float fm[4], fs[4];

  const int tid  = threadIdx.x;
  const int bidx = blockIdx.x;

  for (int i = tid; i < U_SZ * 16; i += 256) {
    int row = i >> 4, c16 = i & 15;
    uint4 val = ((const uint4*)wt_g)[i];
    *(uint4*)&wt[row][c16 * 8] = val;
  }
  if (tid < U_SZ) { wb_s[tid] = wb[tid]; v_s[tid] = v[tid]; }
  __syncthreads();

  const int w  = tid >> 6;          // wave 0..3 -> rows w*16..w*16+15 of tile
  const int l  = tid & 63;
  const int lr = l & 15;            // A row within the wave's 16-row subtile
  const int lh = l >> 4;            // k-subchunk / D-row group
  const float vbias = vb[0];

  const int b        = bidx >> 4;
  const int row0     = (bidx & 15) * (TILES_PER_BLK * T_TILE);
  const float* xbase = x + ((size_t)b * T_SZ + row0 + w * 16 + lr) * D_SZ + lh * 8;

  float4 pf[8];
#pragma unroll
  for (int kt = 0; kt < 4; ++kt) {
    pf[kt * 2]     = *(const float4*)(xbase + kt * 32);
    pf[kt * 2 + 1] = *(const float4*)(xbase + kt * 32 + 4);
  }
  short8 afrag[4];
  cvt_tile(pf, afrag);

  float m_run = -3.0e38f, s_run = 0.0f;
  float rc[4][8];
#pragma unroll
  for (int kt = 0; kt < 4; ++kt)
#pragma unroll
    for (int j = 0; j < 8; ++j) rc[kt][j] = 0.0f;

  for (int it = 0; it < TILES_PER_BLK; ++it) {
    // issue next tile's loads; they stay outstanding across the whole body
    if (it + 1 < TILES_PER_BLK) {
      const float* p = xbase + (size_t)(it + 1) * T_TILE * D_SZ;
#pragma unroll
      for (int kt = 0; kt < 4; ++kt) {
        pf[kt * 2]     = *(const float4*)(p + kt * 32);
        pf[kt * 2 + 1] = *(const float4*)(p + kt * 32 + 4);
      }
    }

    // ---- logits: 8 u-tiles x 4 k-tiles MFMA + tanh + v-weighted u-sum ----
    float lg[4] = {0.f, 0.f, 0.f, 0.f};
#pragma unroll
    for (int ut = 0; ut < 8; ++ut) {
      f32x4 acc = {0.f, 0.f, 0.f, 0.f};
#pragma unroll
      for (int kt = 0; kt < 4; ++kt) {
        short8 bfrag = *(const short8*)&wt[ut * 16 + lr][kt * 32 + lh * 8];
        acc = __builtin_amdgcn_mfma_f32_16x16x32_bf16(afrag[kt], bfrag, acc, 0, 0, 0);
      }
      const float wbv = wb_s[ut * 16 + lr];
      const float vv  = v_s[ut * 16 + lr];
#pragma unroll
      for (int r = 0; r < 4; ++r)
        lg[r] += fast_tanh(acc[r] + wbv) * vv;
    }
#pragma unroll
    for (int r = 0; r < 4; ++r) lg[r] = row_reduce16(lg[r]);
    if (lr == 15) {
#pragma unroll
      for (int r = 0; r < 4; ++r)
        logits[w][lh * 4 + r] = lg[r] + vbias;   // wave-private: no barrier
    }

    // ---- per-wave online softmax over this tile's 16 rows ----
    float lv = logits[w][lr];         // same-wave LDS RAW: lgkmcnt only
    float mx = lv;
#pragma unroll
    for (int k = 1; k <= 8; k <<= 1) mx = fmaxf(mx, __shfl_xor(mx, k, 64));
    const float m_new = fmaxf(m_run, mx);
    const float e_old = __expf(m_run - m_new);
    const float pr    = __expf(lv - m_new);     // own row's weight, final scale
    float ss = pr;
#pragma unroll
    for (int k = 1; k <= 8; k <<= 1) ss += __shfl_xor(ss, k, 64);
    s_run = s_run * e_old + ss;
    m_run = m_new;

    // ---- context: rc = rc*e_old + sum_rows pr*x (DPP reduce over 16 rows) --
#pragma unroll
    for (int kt = 0; kt < 4; ++kt) {
#pragma unroll
      for (int j = 0; j < 8; ++j) {
        float cs = row_reduce16(pr * bf2f((unsigned short)afrag[kt][j]));
        rc[kt][j] = fmaf(rc[kt][j], e_old, cs);
      }
    }

    // ---- convert prefetched fp32 -> afrag (the only vmcnt wait) ----
    if (it + 1 < TILES_PER_BLK) cvt_tile(pf, afrag);
  }

  // ---- one-time cross-wave merge ----
  if (l == 0) { fm[w] = m_run; fs[w] = s_run; }
  __syncthreads();
  const float m_blk = fmaxf(fmaxf(fm[0], fm[1]), fmaxf(fm[2], fm[3]));
  const float e_w   = __expf(m_run - m_blk);
  if (lr == 15) {
#pragma unroll
    for (int kt = 0; kt < 4; ++kt) {
      f32x4 v0 = {rc[kt][0] * e_w, rc[kt][1] * e_w, rc[kt][2] * e_w, rc[kt][3] * e_w};
      f32x4 v1 = {rc[kt][4] * e_w, rc[kt][5] * e_w, rc[kt][6] * e_w, rc[kt][7] * e_w};
      *(f32x4*)&fin[w][kt * 32 + lh * 8]     = v0;
      *(f32x4*)&fin[w][kt * 32 + lh * 8 + 4] = v1;
    }
  }
  __syncthreads();

  float* pb = pbuf + (size_t)bidx * P_STRIDE;
  if (tid < 128) {
    pb[tid] = fin[0][tid] + fin[1][tid] + fin[2][tid] + fin[3][tid];
  } else if (tid == 128) {
    pb[128] = m_blk;
  } else if (tid == 129) {
    float sb = fs[0] * __expf(fm[0] - m_blk) + fs[1] * __expf(fm[1] - m_blk)
             + fs[2] * __expf(fm[2] - m_blk) + fs[3] * __expf(fm[3] - m_blk);
    pb[129] = sb;
  }
}

// ---------------------------------------------------------------------------
// Kernel 2: combine 16 block-partials per batch with global softmax rescale
// ---------------------------------------------------------------------------
__global__ __launch_bounds__(128) void k_combine(const float* __restrict__ pbuf,
                                                 float* __restrict__ out)
{
  const int b = blockIdx.x, tid = threadIdx.x;
  __shared__ float sm[16], sden[16];
  const float* base = pbuf + (size_t)b * 16 * P_STRIDE;

  if (tid < 16) {
    sm[tid]   = base[tid * P_STRIDE + 128];
    sden[tid] = base[tid * P_STRIDE + 129];
  }
  __syncthreads();

  float mx = -3.0e38f;
#pragma unroll
  for (int i = 0; i < 16; ++i) mx = fmaxf(mx, sm[i]);
  float den = 0.0f, c = 0.0f;
#pragma unroll
  for (int i = 0; i < 16; ++i) {
    float e = __expf(sm[i] - mx);
    den += sden[i] * e;
    c = fmaf(base[(size_t)i * P_STRIDE + tid], e, c);
  }
  out[b * D_SZ + tid] = c / den;
}

// ---------------------------------------------------------------------------
extern "C" void kernel_launch(void* const* d_in, const int* in_sizes, int n_in,
                              void* d_out, int out_size, void* d_ws, size_t ws_size,
                              hipStream_t stream) {
  const float* x  = (const float*)d_in[0];  // [B,T,D]
  const float* wk = (const float*)d_in[1];  // [D,U]
  const float* wb = (const float*)d_in[2];  // [U]
  const float* vk = (const float*)d_in[3];  // [U,1]
  const float* vb = (const float*)d_in[4];  // [1]
  float* out = (float*)d_out;               // [B,D]

  unsigned short* wt = (unsigned short*)d_ws;       // 32 KB bf16 Wt[u][d]
  float* pbuf = (float*)((char*)d_ws + 32768);      // 1024 * 132 floats

  k_prep<<<64, 256, 0, stream>>>(wk, wt);
  k_partial<<<GRID_P, 256, 0, stream>>>(x, wt, wb, vk, vb, pbuf);
  k_combine<<<B_SZ, 128, 0, stream>>>(pbuf, out);
}

// Round 8
// 65.009 us; speedup vs baseline: 1.3585x; 1.3585x over previous
//
#include <hip/hip_runtime.h>
#include <hip/hip_bf16.h>

typedef __attribute__((ext_vector_type(8))) short short8;
typedef __attribute__((ext_vector_type(4))) float f32x4;

#define B_SZ 64
#define T_SZ 8192
#define D_SZ 128
#define U_SZ 128
#define T_TILE 64
#define GRID_P 1024
#define TILES_PER_BLK 8           /* 1024 blocks x 8 tiles x 64 rows = 64*8192 */
#define P_STRIDE 132              /* c[128] + m + s, padded */
#define WT_LD 136                 /* bf16 row stride: 272B */

__device__ __forceinline__ unsigned short f2bf(float f) {
  unsigned int u = __builtin_bit_cast(unsigned int, f);
  u += 0x7fffu + ((u >> 16) & 1u);
  return (unsigned short)(u >> 16);
}

__device__ __forceinline__ float bf2f(unsigned short s) {
  return __builtin_bit_cast(float, (unsigned int)s << 16);
}

__device__ __forceinline__ float fast_tanh(float x) {
  float e = __expf(2.0f * x);
  return 1.0f - 2.0f * __builtin_amdgcn_rcpf(e + 1.0f);
}

// DPP row-reduce within each 16-lane row (VALU pipe only).
template<int CTRL>
__device__ __forceinline__ float dpp_add(float v) {
  int t = __builtin_amdgcn_update_dpp(0, __builtin_bit_cast(int, v),
                                      CTRL, 0xf, 0xf, true);
  return v + __builtin_bit_cast(float, t);
}
__device__ __forceinline__ float row_reduce16(float v) {
  v = dpp_add<0x118>(v);  // row_shr:8
  v = dpp_add<0x114>(v);  // row_shr:4
  v = dpp_add<0x112>(v);  // row_shr:2
  v = dpp_add<0x111>(v);  // row_shr:1
  return v;               // lane lr==15 of each 16-lane row holds the sum
}

__device__ __forceinline__ void cvt_tile(const float4 pf[8], short8 afrag[4]) {
#pragma unroll
  for (int kt = 0; kt < 4; ++kt) {
    short8 a;
#pragma unroll
    for (int j = 0; j < 4; ++j) {
      float4 f = pf[kt * 2 + (j >> 1)];
      a[j * 2]     = (short)f2bf(j & 1 ? f.z : f.x);
      a[j * 2 + 1] = (short)f2bf(j & 1 ? f.w : f.y);
    }
    afrag[kt] = a;
  }
}

// ---------------------------------------------------------------------------
// Kernel 0: W [d][u] fp32 -> Wt [u][d] bf16 in workspace (once, tiny)
// ---------------------------------------------------------------------------
__global__ void k_prep(const float* __restrict__ wk, unsigned short* __restrict__ wt) {
  int i = blockIdx.x * 256 + threadIdx.x;
  if (i < D_SZ * U_SZ) {
    int d = i >> 7, u = i & 127;
    wt[u * D_SZ + d] = f2bf(wk[i]);
  }
}

// ---------------------------------------------------------------------------
// Kernel 1: 1024 blocks x 8 contiguous 64-row tiles. Per-wave online softmax
// (no cross-wave deps in the loop). The SINGLE __syncthreads() per tile sits
// at the END of the body, right before cvt_tile: it is a pure scheduling
// fence — next-tile loads issue at the top (pinned there by sched_barrier(0)
// and the WAR on pf vs the previous cvt), stay in flight across the entire
// compute body, and the compiler's vmcnt(0) drain lands after all compute.
// (R6 had no barrier: the scheduler sank the loads to their use to shrink
// the 32-VGPR live range, serializing load->cvt->MFMA. R5 drained too early.)
// Context is accumulated PER LANE (own row x own weight, wave-uniform e_old
// rescale); the 16-row DPP reduce runs once after the loop, not per tile.
// ---------------------------------------------------------------------------
__global__ __launch_bounds__(256) void k_partial(
    const float* __restrict__ x, const unsigned short* __restrict__ wt_g,
    const float* __restrict__ wb, const float* __restrict__ v,
    const float* __restrict__ vb, float* __restrict__ pbuf)
{
  __shared__ unsigned short wt[U_SZ][WT_LD];  // 34816 B
  __shared__ float wb_s[U_SZ], v_s[U_SZ];     // 1 KB
  __shared__ float logits[4][16];             // wave-private slices
  __shared__ float fin[4][D_SZ];              // final merge buffers
  __shared__ float fm[4], fs[4];

  const int tid  = threadIdx.x;
  const int bidx = blockIdx.x;

  for (int i = tid; i < U_SZ * 16; i += 256) {
    int row = i >> 4, c16 = i & 15;
    uint4 val = ((const uint4*)wt_g)[i];
    *(uint4*)&wt[row][c16 * 8] = val;
  }
  if (tid < U_SZ) { wb_s[tid] = wb[tid]; v_s[tid] = v[tid]; }
  __syncthreads();

  const int w  = tid >> 6;          // wave 0..3 -> rows w*16..w*16+15 of tile
  const int l  = tid & 63;
  const int lr = l & 15;            // A row within the wave's 16-row subtile
  const int lh = l >> 4;            // k-subchunk / D-col group
  const float vbias = vb[0];

  const int b        = bidx >> 4;
  const int row0     = (bidx & 15) * (TILES_PER_BLK * T_TILE);
  const float* xbase = x + ((size_t)b * T_SZ + row0 + w * 16 + lr) * D_SZ + lh * 8;

  float4 pf[8];
#pragma unroll
  for (int kt = 0; kt < 4; ++kt) {
    pf[kt * 2]     = *(const float4*)(xbase + kt * 32);
    pf[kt * 2 + 1] = *(const float4*)(xbase + kt * 32 + 4);
  }
  short8 afrag[4];
  cvt_tile(pf, afrag);

  float m_run = -3.0e38f, s_run = 0.0f;
  float rc[4][8];
#pragma unroll
  for (int kt = 0; kt < 4; ++kt)
#pragma unroll
    for (int j = 0; j < 8; ++j) rc[kt][j] = 0.0f;

  for (int it = 0; it < TILES_PER_BLK; ++it) {
    // issue next tile's loads; pinned at the top by sched_barrier below
    if (it + 1 < TILES_PER_BLK) {
      const float* p = xbase + (size_t)(it + 1) * T_TILE * D_SZ;
#pragma unroll
      for (int kt = 0; kt < 4; ++kt) {
        pf[kt * 2]     = *(const float4*)(p + kt * 32);
        pf[kt * 2 + 1] = *(const float4*)(p + kt * 32 + 4);
      }
      __builtin_amdgcn_sched_barrier(0);  // loads may not sink below this
    }

    // ---- logits: 8 u-tiles x 4 k-tiles MFMA + tanh + v-weighted u-sum ----
    float lg[4] = {0.f, 0.f, 0.f, 0.f};
#pragma unroll
    for (int ut = 0; ut < 8; ++ut) {
      f32x4 acc = {0.f, 0.f, 0.f, 0.f};
#pragma unroll
      for (int kt = 0; kt < 4; ++kt) {
        short8 bfrag = *(const short8*)&wt[ut * 16 + lr][kt * 32 + lh * 8];
        acc = __builtin_amdgcn_mfma_f32_16x16x32_bf16(afrag[kt], bfrag, acc, 0, 0, 0);
      }
      const float wbv = wb_s[ut * 16 + lr];
      const float vv  = v_s[ut * 16 + lr];
#pragma unroll
      for (int r = 0; r < 4; ++r)
        lg[r] += fast_tanh(acc[r] + wbv) * vv;
    }
#pragma unroll
    for (int r = 0; r < 4; ++r) lg[r] = row_reduce16(lg[r]);
    if (lr == 15) {
#pragma unroll
      for (int r = 0; r < 4; ++r)
        logits[w][lh * 4 + r] = lg[r] + vbias;   // wave-private: no barrier
    }

    // ---- per-wave online softmax over this tile's 16 rows ----
    float lv = logits[w][lr];         // same-wave LDS RAW: lgkmcnt only
    float mx = lv;
#pragma unroll
    for (int k = 1; k <= 8; k <<= 1) mx = fmaxf(mx, __shfl_xor(mx, k, 64));
    const float m_new = fmaxf(m_run, mx);
    const float e_old = __expf(m_run - m_new);
    const float pr    = __expf(lv - m_new);     // own row's weight
    float ss = pr;
#pragma unroll
    for (int k = 1; k <= 8; k <<= 1) ss += __shfl_xor(ss, k, 64);
    s_run = s_run * e_old + ss;
    m_run = m_new;

    // ---- per-lane context accumulate (no per-tile reduce) ----
#pragma unroll
    for (int kt = 0; kt < 4; ++kt) {
#pragma unroll
      for (int j = 0; j < 8; ++j) {
        rc[kt][j] = fmaf(rc[kt][j], e_old,
                         pr * bf2f((unsigned short)afrag[kt][j]));
      }
    }

    // ---- scheduling fence: drain AFTER all compute, then convert ----
    __syncthreads();
    if (it + 1 < TILES_PER_BLK) cvt_tile(pf, afrag);
  }

  // ---- one-time 16-row reduce + cross-wave merge ----
  if (l == 0) { fm[w] = m_run; fs[w] = s_run; }
  __syncthreads();
  const float m_blk = fmaxf(fmaxf(fm[0], fm[1]), fmaxf(fm[2], fm[3]));
  const float e_w   = __expf(m_run - m_blk);
#pragma unroll
  for (int kt = 0; kt < 4; ++kt) {
    float cs[8];
#pragma unroll
    for (int j = 0; j < 8; ++j) cs[j] = row_reduce16(rc[kt][j]);
    if (lr == 15) {
      f32x4 v0 = {cs[0] * e_w, cs[1] * e_w, cs[2] * e_w, cs[3] * e_w};
      f32x4 v1 = {cs[4] * e_w, cs[5] * e_w, cs[6] * e_w, cs[7] * e_w};
      *(f32x4*)&fin[w][kt * 32 + lh * 8]     = v0;
      *(f32x4*)&fin[w][kt * 32 + lh * 8 + 4] = v1;
    }
  }
  __syncthreads();

  float* pb = pbuf + (size_t)bidx * P_STRIDE;
  if (tid < 128) {
    pb[tid] = fin[0][tid] + fin[1][tid] + fin[2][tid] + fin[3][tid];
  } else if (tid == 128) {
    pb[128] = m_blk;
  } else if (tid == 129) {
    float sb = fs[0] * __expf(fm[0] - m_blk) + fs[1] * __expf(fm[1] - m_blk)
             + fs[2] * __expf(fm[2] - m_blk) + fs[3] * __expf(fm[3] - m_blk);
    pb[129] = sb;
  }
}

// ---------------------------------------------------------------------------
// Kernel 2: combine 16 block-partials per batch with global softmax rescale
// ---------------------------------------------------------------------------
__global__ __launch_bounds__(128) void k_combine(const float* __restrict__ pbuf,
                                                 float* __restrict__ out)
{
  const int b = blockIdx.x, tid = threadIdx.x;
  __shared__ float sm[16], sden[16];
  const float* base = pbuf + (size_t)b * 16 * P_STRIDE;

  if (tid < 16) {
    sm[tid]   = base[tid * P_STRIDE + 128];
    sden[tid] = base[tid * P_STRIDE + 129];
  }
  __syncthreads();

  float mx = -3.0e38f;
#pragma unroll
  for (int i = 0; i < 16; ++i) mx = fmaxf(mx, sm[i]);
  float den = 0.0f, c = 0.0f;
#pragma unroll
  for (int i = 0; i < 16; ++i) {
    float e = __expf(sm[i] - mx);
    den += sden[i] * e;
    c = fmaf(base[(size_t)i * P_STRIDE + tid], e, c);
  }
  out[b * D_SZ + tid] = c / den;
}

// ---------------------------------------------------------------------------
extern "C" void kernel_launch(void* const* d_in, const int* in_sizes, int n_in,
                              void* d_out, int out_size, void* d_ws, size_t ws_size,
                              hipStream_t stream) {
  const float* x  = (const float*)d_in[0];  // [B,T,D]
  const float* wk = (const float*)d_in[1];  // [D,U]
  const float* wb = (const float*)d_in[2];  // [U]
  const float* vk = (const float*)d_in[3];  // [U,1]
  const float* vb = (const float*)d_in[4];  // [1]
  float* out = (float*)d_out;               // [B,D]

  unsigned short* wt = (unsigned short*)d_ws;       // 32 KB bf16 Wt[u][d]
  float* pbuf = (float*)((char*)d_ws + 32768);      // 1024 * 132 floats

  k_prep<<<64, 256, 0, stream>>>(wk, wt);
  k_partial<<<GRID_P, 256, 0, stream>>>(x, wt, wb, vk, vb, pbuf);
  k_combine<<<B_SZ, 128, 0, stream>>>(pbuf, out);
}

// Round 9
// 63.858 us; speedup vs baseline: 1.3830x; 1.0180x over previous
//
#include <hip/hip_runtime.h>
#include <hip/hip_bf16.h>

typedef __attribute__((ext_vector_type(8))) short short8;
typedef __attribute__((ext_vector_type(4))) float f32x4;

#define B_SZ 64
#define T_SZ 8192
#define D_SZ 128
#define U_SZ 128
#define T_TILE 64
#define GRID_P 1024
#define TILES_PER_BLK 8           /* 1024 blocks x 8 tiles x 64 rows = 64*8192 */
#define P_STRIDE 132              /* c[128] + m + s, padded */
#define WT_LD 136                 /* bf16 row stride: 272B */

__device__ __forceinline__ unsigned short f2bf(float f) {
  unsigned int u = __builtin_bit_cast(unsigned int, f);
  u += 0x7fffu + ((u >> 16) & 1u);
  return (unsigned short)(u >> 16);
}

__device__ __forceinline__ float bf2f(unsigned short s) {
  return __builtin_bit_cast(float, (unsigned int)s << 16);
}

__device__ __forceinline__ float fast_tanh(float x) {
  float e = __expf(2.0f * x);
  return 1.0f - 2.0f * __builtin_amdgcn_rcpf(e + 1.0f);
}

// DPP row-reduce within each 16-lane row (VALU pipe only).
template<int CTRL>
__device__ __forceinline__ float dpp_add(float v) {
  int t = __builtin_amdgcn_update_dpp(0, __builtin_bit_cast(int, v),
                                      CTRL, 0xf, 0xf, true);
  return v + __builtin_bit_cast(float, t);
}
__device__ __forceinline__ float row_reduce16(float v) {
  v = dpp_add<0x118>(v);  // row_shr:8
  v = dpp_add<0x114>(v);  // row_shr:4
  v = dpp_add<0x112>(v);  // row_shr:2
  v = dpp_add<0x111>(v);  // row_shr:1
  return v;               // lane lr==15 of each 16-lane row holds the sum
}

__device__ __forceinline__ void cvt_tile(const float4 pf[8], short8 afrag[4]) {
#pragma unroll
  for (int kt = 0; kt < 4; ++kt) {
    short8 a;
#pragma unroll
    for (int j = 0; j < 4; ++j) {
      float4 f = pf[kt * 2 + (j >> 1)];
      a[j * 2]     = (short)f2bf(j & 1 ? f.z : f.x);
      a[j * 2 + 1] = (short)f2bf(j & 1 ? f.w : f.y);
    }
    afrag[kt] = a;
  }
}

// ---------------------------------------------------------------------------
// Kernel 0: W [d][u] fp32 -> Wt [u][d] bf16 in workspace (once, tiny)
// ---------------------------------------------------------------------------
__global__ void k_prep(const float* __restrict__ wk, unsigned short* __restrict__ wt) {
  int i = blockIdx.x * 256 + threadIdx.x;
  if (i < D_SZ * U_SZ) {
    int d = i >> 7, u = i & 127;
    wt[u * D_SZ + d] = f2bf(wk[i]);
  }
}

// ---------------------------------------------------------------------------
// Kernel 1: 1024 blocks x 8 contiguous 64-row tiles. Per-wave online softmax
// (no cross-wave deps in the loop). Schedule pinning WITHOUT block sync:
//   sched_barrier(0) after load-issue  -> loads cannot sink into the body
//   sched_barrier(0) before cvt_tile   -> cvt (and its vmcnt wait) cannot
//                                         hoist above the compute body
// This keeps R7's per-wave instruction schedule (loads in flight across the
// whole body) while letting the 4 waves drift -> smoother HBM issue, no
// per-tile block-alignment stall, no compiler vmcnt(0)+s_barrier drain.
// (R6 regressed because cvt's vmcnt(0) hoisted right after the loads; R7
// fixed it with __syncthreads, which over-synchronized.)
// ---------------------------------------------------------------------------
__global__ __launch_bounds__(256) void k_partial(
    const float* __restrict__ x, const unsigned short* __restrict__ wt_g,
    const float* __restrict__ wb, const float* __restrict__ v,
    const float* __restrict__ vb, float* __restrict__ pbuf)
{
  __shared__ unsigned short wt[U_SZ][WT_LD];  // 34816 B
  __shared__ float wb_s[U_SZ], v_s[U_SZ];     // 1 KB
  __shared__ float logits[4][16];             // wave-private slices
  __shared__ float fin[4][D_SZ];              // final merge buffers
  __shared__ float fm[4], fs[4];

  const int tid  = threadIdx.x;
  const int bidx = blockIdx.x;

  for (int i = tid; i < U_SZ * 16; i += 256) {
    int row = i >> 4, c16 = i & 15;
    uint4 val = ((const uint4*)wt_g)[i];
    *(uint4*)&wt[row][c16 * 8] = val;
  }
  if (tid < U_SZ) { wb_s[tid] = wb[tid]; v_s[tid] = v[tid]; }
  __syncthreads();

  const int w  = tid >> 6;          // wave 0..3 -> rows w*16..w*16+15 of tile
  const int l  = tid & 63;
  const int lr = l & 15;            // A row within the wave's 16-row subtile
  const int lh = l >> 4;            // k-subchunk / D-col group
  const float vbias = vb[0];

  const int b        = bidx >> 4;
  const int row0     = (bidx & 15) * (TILES_PER_BLK * T_TILE);
  const float* xbase = x + ((size_t)b * T_SZ + row0 + w * 16 + lr) * D_SZ + lh * 8;

  float4 pf[8];
#pragma unroll
  for (int kt = 0; kt < 4; ++kt) {
    pf[kt * 2]     = *(const float4*)(xbase + kt * 32);
    pf[kt * 2 + 1] = *(const float4*)(xbase + kt * 32 + 4);
  }
  short8 afrag[4];
  cvt_tile(pf, afrag);

  float m_run = -3.0e38f, s_run = 0.0f;
  float rc[4][8];
#pragma unroll
  for (int kt = 0; kt < 4; ++kt)
#pragma unroll
    for (int j = 0; j < 8; ++j) rc[kt][j] = 0.0f;

  for (int it = 0; it < TILES_PER_BLK; ++it) {
    // issue next tile's loads; pinned at the top by sched_barrier below
    if (it + 1 < TILES_PER_BLK) {
      const float* p = xbase + (size_t)(it + 1) * T_TILE * D_SZ;
#pragma unroll
      for (int kt = 0; kt < 4; ++kt) {
        pf[kt * 2]     = *(const float4*)(p + kt * 32);
        pf[kt * 2 + 1] = *(const float4*)(p + kt * 32 + 4);
      }
      __builtin_amdgcn_sched_barrier(0);  // loads may not sink below this
    }

    // ---- logits: 8 u-tiles x 4 k-tiles MFMA + tanh + v-weighted u-sum ----
    float lg[4] = {0.f, 0.f, 0.f, 0.f};
#pragma unroll
    for (int ut = 0; ut < 8; ++ut) {
      f32x4 acc = {0.f, 0.f, 0.f, 0.f};
#pragma unroll
      for (int kt = 0; kt < 4; ++kt) {
        short8 bfrag = *(const short8*)&wt[ut * 16 + lr][kt * 32 + lh * 8];
        acc = __builtin_amdgcn_mfma_f32_16x16x32_bf16(afrag[kt], bfrag, acc, 0, 0, 0);
      }
      const float wbv = wb_s[ut * 16 + lr];
      const float vv  = v_s[ut * 16 + lr];
#pragma unroll
      for (int r = 0; r < 4; ++r)
        lg[r] += fast_tanh(acc[r] + wbv) * vv;
    }
#pragma unroll
    for (int r = 0; r < 4; ++r) lg[r] = row_reduce16(lg[r]);
    if (lr == 15) {
#pragma unroll
      for (int r = 0; r < 4; ++r)
        logits[w][lh * 4 + r] = lg[r] + vbias;   // wave-private: no barrier
    }

    // ---- per-wave online softmax over this tile's 16 rows ----
    float lv = logits[w][lr];         // same-wave LDS RAW: lgkmcnt only
    float mx = lv;
#pragma unroll
    for (int k = 1; k <= 8; k <<= 1) mx = fmaxf(mx, __shfl_xor(mx, k, 64));
    const float m_new = fmaxf(m_run, mx);
    const float e_old = __expf(m_run - m_new);
    const float pr    = __expf(lv - m_new);     // own row's weight
    float ss = pr;
#pragma unroll
    for (int k = 1; k <= 8; k <<= 1) ss += __shfl_xor(ss, k, 64);
    s_run = s_run * e_old + ss;
    m_run = m_new;

    // ---- per-lane context accumulate (no per-tile reduce) ----
#pragma unroll
    for (int kt = 0; kt < 4; ++kt) {
#pragma unroll
      for (int j = 0; j < 8; ++j) {
        rc[kt][j] = fmaf(rc[kt][j], e_old,
                         pr * bf2f((unsigned short)afrag[kt][j]));
      }
    }

    // ---- scheduling fence only (no block sync): cvt may not hoist up ----
    __builtin_amdgcn_sched_barrier(0);
    if (it + 1 < TILES_PER_BLK) cvt_tile(pf, afrag);
  }

  // ---- one-time 16-row reduce + cross-wave merge ----
  if (l == 0) { fm[w] = m_run; fs[w] = s_run; }
  __syncthreads();
  const float m_blk = fmaxf(fmaxf(fm[0], fm[1]), fmaxf(fm[2], fm[3]));
  const float e_w   = __expf(m_run - m_blk);
#pragma unroll
  for (int kt = 0; kt < 4; ++kt) {
    float cs[8];
#pragma unroll
    for (int j = 0; j < 8; ++j) cs[j] = row_reduce16(rc[kt][j]);
    if (lr == 15) {
      f32x4 v0 = {cs[0] * e_w, cs[1] * e_w, cs[2] * e_w, cs[3] * e_w};
      f32x4 v1 = {cs[4] * e_w, cs[5] * e_w, cs[6] * e_w, cs[7] * e_w};
      *(f32x4*)&fin[w][kt * 32 + lh * 8]     = v0;
      *(f32x4*)&fin[w][kt * 32 + lh * 8 + 4] = v1;
    }
  }
  __syncthreads();

  float* pb = pbuf + (size_t)bidx * P_STRIDE;
  if (tid < 128) {
    pb[tid] = fin[0][tid] + fin[1][tid] + fin[2][tid] + fin[3][tid];
  } else if (tid == 128) {
    pb[128] = m_blk;
  } else if (tid == 129) {
    float sb = fs[0] * __expf(fm[0] - m_blk) + fs[1] * __expf(fm[1] - m_blk)
             + fs[2] * __expf(fm[2] - m_blk) + fs[3] * __expf(fm[3] - m_blk);
    pb[129] = sb;
  }
}

// ---------------------------------------------------------------------------
// Kernel 2: combine 16 block-partials per batch with global softmax rescale
// ---------------------------------------------------------------------------
__global__ __launch_bounds__(128) void k_combine(const float* __restrict__ pbuf,
                                                 float* __restrict__ out)
{
  const int b = blockIdx.x, tid = threadIdx.x;
  __shared__ float sm[16], sden[16];
  const float* base = pbuf + (size_t)b * 16 * P_STRIDE;

  if (tid < 16) {
    sm[tid]   = base[tid * P_STRIDE + 128];
    sden[tid] = base[tid * P_STRIDE + 129];
  }
  __syncthreads();

  float mx = -3.0e38f;
#pragma unroll
  for (int i = 0; i < 16; ++i) mx = fmaxf(mx, sm[i]);
  float den = 0.0f, c = 0.0f;
#pragma unroll
  for (int i = 0; i < 16; ++i) {
    float e = __expf(sm[i] - mx);
    den += sden[i] * e;
    c = fmaf(base[(size_t)i * P_STRIDE + tid], e, c);
  }
  out[b * D_SZ + tid] = c / den;
}

// ---------------------------------------------------------------------------
extern "C" void kernel_launch(void* const* d_in, const int* in_sizes, int n_in,
                              void* d_out, int out_size, void* d_ws, size_t ws_size,
                              hipStream_t stream) {
  const float* x  = (const float*)d_in[0];  // [B,T,D]
  const float* wk = (const float*)d_in[1];  // [D,U]
  const float* wb = (const float*)d_in[2];  // [U]
  const float* vk = (const float*)d_in[3];  // [U,1]
  const float* vb = (const float*)d_in[4];  // [1]
  float* out = (float*)d_out;               // [B,D]

  unsigned short* wt = (unsigned short*)d_ws;       // 32 KB bf16 Wt[u][d]
  float* pbuf = (float*)((char*)d_ws + 32768);      // 1024 * 132 floats

  k_prep<<<64, 256, 0, stream>>>(wk, wt);
  k_partial<<<GRID_P, 256, 0, stream>>>(x, wt, wb, vk, vb, pbuf);
  k_combine<<<B_SZ, 128, 0, stream>>>(pbuf, out);
}